// Round 1
// baseline (187.528 us; speedup 1.0000x reference)
//
#include <hip/hip_runtime.h>

typedef __attribute__((ext_vector_type(8))) short bf16x8;
typedef __attribute__((ext_vector_type(4))) float f32x4;

__device__ __forceinline__ unsigned short f2bf(float f) {
    unsigned int u = __float_as_uint(f);
    u = (u + 0x7FFFu + ((u >> 16) & 1u)) >> 16;   // round-to-nearest-even
    return (unsigned short)u;
}

// ---------------------------------------------------------------------------
// Kernel 1: partial Wc = w_patch @ [w_reg | w_obj], split over 6 d-chunks.
// grid (6 d-chunks, 12 k-tiles), block 256. Writes part[dc][k][48] fp32.
// ---------------------------------------------------------------------------
__global__ __launch_bounds__(256) void wcomb_partial(
        const float* __restrict__ wp, const float* __restrict__ wreg,
        const float* __restrict__ wobj, float* __restrict__ part) {
    __shared__ float Al[64][132];   // 64 k-rows x 128 d (pad 132)
    __shared__ float Bl[48][132];   // 48 n x 128 d (transposed, pad 132)
    const int t  = threadIdx.x;
    const int d0 = blockIdx.x * 128;
    const int k0 = blockIdx.y * 64;

    #pragma unroll
    for (int i = 0; i < 8; ++i) {                       // A: 64x128 floats
        int e = i * 256 + t;
        int row = e >> 5, dq = e & 31;
        *(f32x4*)&Al[row][dq * 4] =
            *(const f32x4*)&wp[(size_t)(k0 + row) * 768 + d0 + dq * 4];
    }
    #pragma unroll
    for (int i = 0; i < 24; ++i) {                      // B: 128x48 scalars
        int e = i * 256 + t;
        int d = e / 48, n = e - d * 48;
        float v = 0.f;
        if (n < 36)      v = wreg[(size_t)(d0 + d) * 36 + n];
        else if (n < 45) v = wobj[(size_t)(d0 + d) * 9 + (n - 36)];
        Bl[n][d] = v;
    }
    __syncthreads();

    const int r0 = (t & 15) * 4;      // 4 k-rows per thread
    const int n0 = (t >> 4) * 3;      // 3 n-cols per thread
    float acc[4][3] = {};
    for (int ds = 0; ds < 32; ++ds) {
        f32x4 a[4], bv[3];
        #pragma unroll
        for (int i = 0; i < 4; ++i) a[i] = *(const f32x4*)&Al[r0 + i][ds * 4];
        #pragma unroll
        for (int j = 0; j < 3; ++j) bv[j] = *(const f32x4*)&Bl[n0 + j][ds * 4];
        #pragma unroll
        for (int i = 0; i < 4; ++i)
            #pragma unroll
            for (int j = 0; j < 3; ++j)
                acc[i][j] += a[i].x * bv[j].x + a[i].y * bv[j].y
                           + a[i].z * bv[j].z + a[i].w * bv[j].w;
    }
    #pragma unroll
    for (int i = 0; i < 4; ++i)
        #pragma unroll
        for (int j = 0; j < 3; ++j)
            part[((size_t)blockIdx.x * 768 + k0 + r0 + i) * 48 + n0 + j] = acc[i][j];
}

// ---------------------------------------------------------------------------
// Kernel 2: reduce 6 partial slabs -> Wc_t bf16, TRANSPOSED [48 n][768 k]
// grid (3, 48), block 256.
// ---------------------------------------------------------------------------
__global__ __launch_bounds__(256) void wcomb_reduce(
        const float* __restrict__ part, unsigned short* __restrict__ wct) {
    const int k = blockIdx.x * 256 + threadIdx.x;   // 0..767
    const int n = blockIdx.y;                       // 0..47
    float s = 0.f;
    if (n < 45) {
        #pragma unroll
        for (int dc = 0; dc < 6; ++dc) s += part[((size_t)dc * 768 + k) * 48 + n];
    }
    wct[(size_t)n * 768 + k] = f2bf(s);
}

// ---------------------------------------------------------------------------
// Kernel 3: main fused GEMM + anchor decode.
// grid 512 (= 32 batch x 16 fi-pairs), block 256 (4 waves).
// Per wg: M=64 cells (2 fi x 32 fj), N=48, K=768. bf16 MFMA 16x16x32.
// ---------------------------------------------------------------------------
__global__ __launch_bounds__(256) void detector_main(
        const float* __restrict__ img, const unsigned short* __restrict__ wct,
        const float* __restrict__ breg, const float* __restrict__ bobj,
        float* __restrict__ out) {
    __shared__ unsigned short A[64][72];   // 64 cells x 64 k (pad 72) bf16
    __shared__ float Co[64][49];           // C tile for decode

    const int t    = threadIdx.x;
    const int lane = t & 63;
    const int wid  = t >> 6;               // wave id = M-tile
    const int cl   = lane & 15;
    const int q    = lane >> 4;
    const int b    = blockIdx.x >> 4;
    const int fi0  = (blockIdx.x & 15) * 2;
    const float* img_b = img + (size_t)b * 3 * 512 * 512;

    f32x4 acc[3];
    #pragma unroll
    for (int nt = 0; nt < 3; ++nt) acc[nt] = (f32x4){0.f, 0.f, 0.f, 0.f};

    for (int cc = 0; cc < 12; ++cc) {      // K-chunks of 64 (= channel c, 4 patch-rows)
        const int c  = cc >> 2;
        const int p0 = (cc & 3) * 4;
        // ---- stage A: 8 image rows x 512 floats -> bf16 LDS tile ----
        #pragma unroll
        for (int it = 0; it < 2; ++it) {
            int s      = it * 256 + t;
            int row_id = s >> 6, seg = s & 63;
            int fl = row_id >> 2, p = row_id & 3;
            int fj = seg >> 1,    g = seg & 1;
            const float* src = img_b
                + ((size_t)c * 512 + (fi0 + fl) * 16 + p0 + p) * 512 + fj * 16 + g * 8;
            f32x4 v0 = *(const f32x4*)src;
            f32x4 v1 = *(const f32x4*)(src + 4);
            bf16x8 w;
            w[0] = (short)f2bf(v0.x); w[1] = (short)f2bf(v0.y);
            w[2] = (short)f2bf(v0.z); w[3] = (short)f2bf(v0.w);
            w[4] = (short)f2bf(v1.x); w[5] = (short)f2bf(v1.y);
            w[6] = (short)f2bf(v1.z); w[7] = (short)f2bf(v1.w);
            *(bf16x8*)&A[fl * 32 + fj][p * 16 + g * 8] = w;
        }
        __syncthreads();
        // ---- MFMA: 2 k-steps x 3 N-tiles ----
        const int kb = cc * 64 + q * 8;
        #pragma unroll
        for (int ks = 0; ks < 2; ++ks) {
            bf16x8 af = *(const bf16x8*)&A[wid * 16 + cl][ks * 32 + q * 8];
            #pragma unroll
            for (int nt = 0; nt < 3; ++nt) {
                bf16x8 bfr = *(const bf16x8*)&wct[(size_t)(nt * 16 + cl) * 768 + kb + ks * 32];
                acc[nt] = __builtin_amdgcn_mfma_f32_16x16x32_bf16(af, bfr, acc[nt], 0, 0, 0);
            }
        }
        __syncthreads();
    }

    // ---- C frags -> LDS (col = lane&15, row = quad*4 + reg) ----
    #pragma unroll
    for (int nt = 0; nt < 3; ++nt)
        #pragma unroll
        for (int r = 0; r < 4; ++r)
            Co[wid * 16 + q * 4 + r][nt * 16 + cl] = acc[nt][r];
    __syncthreads();

    // ---- anchor decode: 64 cells x 9 anchors = 576 output rows of 7 ----
    for (int rr = t; rr < 576; rr += 256) {
        int cell = rr / 9, k = rr - cell * 9;
        int fl = cell >> 5, fj = cell & 31;
        int fi = fi0 + fl;
        float v0 = Co[cell][4 * k + 0] + breg[4 * k + 0];
        float v1 = Co[cell][4 * k + 1] + breg[4 * k + 1];
        float v2 = Co[cell][4 * k + 2] + breg[4 * k + 2];
        float v3 = Co[cell][4 * k + 3] + breg[4 * k + 3];
        float lg = Co[cell][36 + k] + bobj[k];
        float obj = 1.f / (1.f + __expf(-lg));
        float wc = (float)(fj * 16) + v0;
        float hc = (float)(fi * 16) + v1;
        float wa = wc + (float)(2 << (k % 3)) * v2;   // BOX_W = 2,4,8 cycling
        float ha = hc + (float)(2 << (k / 3)) * v3;   // BOX_H = 2,2,2,4,4,4,8,8,8
        float* o = out + (size_t)(((b * 32 + fi) * 32 + fj) * 9 + k) * 7;
        o[0] = wc; o[1] = hc; o[2] = wa; o[3] = ha;
        o[4] = (float)b; o[5] = obj; o[6] = (float)k;
    }
}

extern "C" void kernel_launch(void* const* d_in, const int* in_sizes, int n_in,
                              void* d_out, int out_size, void* d_ws, size_t ws_size,
                              hipStream_t stream) {
    const float* img  = (const float*)d_in[0];
    const float* wp   = (const float*)d_in[1];
    const float* wreg = (const float*)d_in[2];
    const float* breg = (const float*)d_in[3];
    const float* wobj = (const float*)d_in[4];
    const float* bobj = (const float*)d_in[5];
    float* out = (float*)d_out;

    float* part = (float*)d_ws;                                     // 884736 B
    unsigned short* wct = (unsigned short*)((char*)d_ws + 6 * 768 * 48 * 4);  // 73728 B

    wcomb_partial<<<dim3(6, 12), 256, 0, stream>>>(wp, wreg, wobj, part);
    wcomb_reduce<<<dim3(3, 48), 256, 0, stream>>>(part, wct);
    detector_main<<<512, 256, 0, stream>>>(img, wct, breg, bobj, out);
}